// Round 4
// baseline (422.722 us; speedup 1.0000x reference)
//
#include <hip/hip_runtime.h>
#include <math.h>
#include <stdint.h>

#define ND 128
#define NNB 32
#define NH 8

typedef __attribute__((ext_vector_type(8))) short bf16x8;
typedef __attribute__((ext_vector_type(4))) float f32x4;
typedef __attribute__((ext_vector_type(8))) unsigned short u16x8;
typedef unsigned short u16;
typedef unsigned int u32;
typedef unsigned long long u64;

// ---- ws layout (bytes); all weights transposed Wt[N][K] bf16, LINEAR ----
#define OFF_QW1T 0ULL
#define OFF_QW2T 32768ULL
#define OFF_GW1T 294912ULL     // [128][32] (K padded 12->32 with zeros)
#define OFF_GW2T 303104ULL
#define OFF_KW1T 335872ULL
#define OFF_KW2T 368640ULL
#define OFF_VW1T 401408ULL
#define OFF_VW2T 434176ULL
#define OFF_DW1T 466944ULL     // [128][1024]
#define OFF_DW2T 729088ULL
#define OFF_Q    761856ULL     // [20096][1024] bf16, linear
#define OFF_ATT  (OFF_Q + 20096ULL * 2048ULL)  // chunk-swizzled by (pid&7)

__device__ __forceinline__ u16 rneb(float f){
    u32 u = __builtin_bit_cast(u32, f);
    u32 r = u + 0x7fffu + ((u >> 16) & 1u);
    return (u16)(r >> 16);
}
__device__ __forceinline__ float elu_f(float v){ return v > 0.f ? v : (__expf(v) - 1.f); }
__device__ __forceinline__ u64 pack4(float a, float b, float c, float d){
    return (u64)rneb(a) | ((u64)rneb(b) << 16) | ((u64)rneb(c) << 32) | ((u64)rneb(d) << 48);
}

// async global->LDS, 16B per lane (linear dest)
#define GLDS16(g, l) __builtin_amdgcn_global_load_lds( \
    (const __attribute__((address_space(1))) u32*)(g), \
    (__attribute__((address_space(3))) u32*)(u32)(u64)(l), 16, 0, 0)

// stage 128 rows of 256B from strided global into [128][256B] LDS tile
__device__ __forceinline__ void stage_rows(char* lds, const char* g, size_t gstride){
    const int t = threadIdx.x;
    const int seg = (t & 15) * 16, rr = t >> 4;
    #pragma unroll
    for (int i = 0; i < 8; i++){
        int row = i * 16 + rr;
        GLDS16(g + (size_t)row * gstride + seg, lds + row * 256 + seg);
    }
}

// fragment read from LDS: row-major [*][128] bf16, byte ^= (row&7)<<4
// serves BOTH A-frag (idx=row) and B-frag (idx=col of B = row of B^T)
__device__ __forceinline__ bf16x8 ldfrag(const u16* base, int row, int kb, int l){
    int r = row + (l & 15);
    int byte = (r << 8) + (((kb << 1) + ((l >> 4) << 4)) ^ ((r & 7) << 4));
    return *(const bf16x8*)((const char*)base + byte);
}
// fragment directly from global Wt[N][K] (linear, row stride kstride bytes)
__device__ __forceinline__ bf16x8 ldfragG(const char* __restrict__ Wt, int n, int kstride, int kb, int l){
    return *(const bf16x8*)(Wt + (size_t)(n + (l & 15)) * (size_t)kstride
                               + (size_t)((kb << 1) + ((l >> 4) << 4)));
}
// RL fragment: [128][32] bf16 rows of 64B, byte ^= (row&3)<<4
__device__ __forceinline__ bf16x8 ldfragRL(const u16* base, int row, int l){
    int r = row + (l & 15);
    int byte = (r << 6) + ((((l >> 4) << 4)) ^ ((r & 3) << 4));
    return *(const bf16x8*)((const char*)base + byte);
}

// NEW-orientation GEMM: Z = Wt(A, global) @ Xact^T(B, LDS row-major)
// Z frag: col (l&15) = activation row, 4-contig regs = out-channels.
__device__ __forceinline__ void gemm_WA(const char* __restrict__ Wt, int kstride, int kbase,
                                        const u16* B, f32x4 acc[4][4]){
    const int t = threadIdx.x, l = t & 63;
    const int m0 = ((t >> 7) & 1) * 64;   // out-channel half
    const int n0 = ((t >> 6) & 1) * 64;   // row half
    bf16x8 aw[4][4];
    #pragma unroll
    for (int kk = 0; kk < 4; kk++)
        #pragma unroll
        for (int i = 0; i < 4; i++)
            aw[kk][i] = ldfragG(Wt, m0 + i * 16, kstride, kbase + kk * 32, l);
    __builtin_amdgcn_s_setprio(1);
    #pragma unroll
    for (int kk = 0; kk < 4; kk++){
        bf16x8 b[4];
        #pragma unroll
        for (int i = 0; i < 4; i++) b[i] = ldfrag(B, n0 + i * 16, kk * 32, l);
        #pragma unroll
        for (int mt = 0; mt < 4; mt++)
            #pragma unroll
            for (int nt = 0; nt < 4; nt++)
                acc[mt][nt] = __builtin_amdgcn_mfma_f32_16x16x32_bf16(aw[kk][mt], b[nt], acc[mt][nt], 0, 0, 0);
    }
    __builtin_amdgcn_s_setprio(0);
}

// OLD-orientation GEMM (for V2): Z = Aact(LDS) @ Wt(B, global)
__device__ __forceinline__ void gemm_AW(const u16* A, const char* __restrict__ Wt,
                                        f32x4 acc[4][4]){
    const int t = threadIdx.x, l = t & 63;
    const int m0 = ((t >> 7) & 1) * 64;
    const int n0 = ((t >> 6) & 1) * 64;
    bf16x8 bw[4][4];
    #pragma unroll
    for (int kk = 0; kk < 4; kk++)
        #pragma unroll
        for (int i = 0; i < 4; i++)
            bw[kk][i] = ldfragG(Wt, n0 + i * 16, 256, kk * 32, l);
    __builtin_amdgcn_s_setprio(1);
    #pragma unroll
    for (int kk = 0; kk < 4; kk++){
        bf16x8 a[4];
        #pragma unroll
        for (int i = 0; i < 4; i++) a[i] = ldfrag(A, m0 + i * 16, kk * 32, l);
        #pragma unroll
        for (int mt = 0; mt < 4; mt++)
            #pragma unroll
            for (int nt = 0; nt < 4; nt++)
                acc[mt][nt] = __builtin_amdgcn_mfma_f32_16x16x32_bf16(a[mt], bw[kk][nt], acc[mt][nt], 0, 0, 0);
    }
    __builtin_amdgcn_s_setprio(0);
}

// ---------------------------------------------------------------------------
// prep: W (Ksrc x N f32) -> Wt (N x Kdst bf16, zero-padded), linear
// ---------------------------------------------------------------------------
struct PrepDesc {
    const float* src[10];
    u64 dstoff[10];
    int N[10], Ksrc[10], Kdst[10];
};

__global__ __launch_bounds__(256) void prep_weights(PrepDesc d, char* ws){
    int tid = blockIdx.x * 256 + threadIdx.x;
    #pragma unroll 1
    for (int m = 0; m < 10; m++){
        int cnt = (d.Kdst[m] * d.N[m]) >> 3;
        if (tid < cnt){
            int N = d.N[m];
            int nn = tid % N, k8 = tid / N;
            const float* s = d.src[m];
            u16x8 pk;
            #pragma unroll
            for (int i = 0; i < 8; i++){
                int k = k8 * 8 + i;
                pk[i] = (k < d.Ksrc[m]) ? rneb(s[(size_t)k * N + nn]) : (u16)0;
            }
            *(u16x8*)(ws + d.dstoff[m] + (u64)nn * (u64)(d.Kdst[m] * 2) + (u64)(k8 * 16)) = pk;
            return;
        }
        tid -= cnt;
    }
}

// ---------------------------------------------------------------------------
// qmlp: Q = elu(F@qW1+qb1)@qW2+qb2 -> bf16 LINEAR Q buffer in ws
// ---------------------------------------------------------------------------
__global__ __launch_bounds__(256, 2) void qmlp_kernel(
    const float* __restrict__ F, const float* __restrict__ qb1, const float* __restrict__ qb2,
    const char* __restrict__ ws, u16* __restrict__ Qg, int n)
{
    __shared__ __align__(16) u16 sIn[16384];
    __shared__ __align__(16) u16 sH[16384];
    const int t = threadIdx.x;
    const int row0 = blockIdx.x * 128;
    const int l = t & 63;
    const int m0 = ((t >> 7) & 1) * 64;
    const int n0 = ((t >> 6) & 1) * 64;
    const int hi = l >> 4;

    // stage F (f32 -> bf16, swizzled) into sIn
    for (int i = t; i < 4096; i += 256){
        int r = i >> 5, c = (i & 31) * 4;
        int gr = row0 + r;
        float4 v = make_float4(0.f, 0.f, 0.f, 0.f);
        if (gr < n) v = *(const float4*)&F[(size_t)gr * ND + c];
        *(u64*)((char*)sIn + (r << 8) + (((c << 1)) ^ ((r & 7) << 4))) = pack4(v.x, v.y, v.z, v.w);
    }
    __syncthreads();

    // L1: 128->128, elu -> sH (packed u64 stores)
    f32x4 acc[4][4];
    #pragma unroll
    for (int i = 0; i < 4; i++)
        #pragma unroll
        for (int j = 0; j < 4; j++) acc[i][j] = 0.f;
    gemm_WA(ws + OFF_QW1T, 256, 0, sIn, acc);
    #pragma unroll
    for (int mt = 0; mt < 4; mt++){
        int ch0 = m0 + mt * 16 + (hi << 2);
        float4 bq = *(const float4*)&qb1[ch0];
        #pragma unroll
        for (int nt = 0; nt < 4; nt++){
            int xrow = n0 + nt * 16 + (l & 15);
            u64 pk = pack4(elu_f(acc[mt][nt][0] + bq.x), elu_f(acc[mt][nt][1] + bq.y),
                           elu_f(acc[mt][nt][2] + bq.z), elu_f(acc[mt][nt][3] + bq.w));
            *(u64*)((char*)sH + (xrow << 8) + (((ch0 << 1)) ^ ((xrow & 7) << 4))) = pk;
        }
    }
    __syncthreads();

    // L2: 128->1024 in 8 column chunks
    for (int ct = 0; ct < 8; ct++){
        f32x4 a2[4][4];
        #pragma unroll
        for (int i = 0; i < 4; i++)
            #pragma unroll
            for (int j = 0; j < 4; j++) a2[i][j] = 0.f;
        gemm_WA(ws + OFF_QW2T + (u64)ct * 32768ULL, 256, 0, sH, a2);
        #pragma unroll
        for (int mt = 0; mt < 4; mt++){
            int ch0 = m0 + mt * 16 + (hi << 2);
            float4 bq = *(const float4*)&qb2[ct * 128 + ch0];
            #pragma unroll
            for (int nt = 0; nt < 4; nt++){
                int xrow = n0 + nt * 16 + (l & 15);
                *(u64*)((char*)sIn + (xrow << 8) + (ch0 << 1)) =
                    pack4(a2[mt][nt][0] + bq.x, a2[mt][nt][1] + bq.y,
                          a2[mt][nt][2] + bq.z, a2[mt][nt][3] + bq.w);
            }
        }
        __syncthreads();
        {
            int row = t >> 1, half = t & 1;
            int gr = row0 + row;
            if (gr < n){
                const char* src = (const char*)sIn + (row << 8) + half * 128;
                char* dst = (char*)Qg + (size_t)gr * 2048 + ct * 256 + half * 128;
                #pragma unroll
                for (int i = 0; i < 8; i++)
                    *(uint4*)(dst + i * 16) = *(const uint4*)(src + i * 16);
            }
        }
        __syncthreads();
    }
}

// ---------------------------------------------------------------------------
// attn: fused geometry + geo/K/V MLPs (MFMA) + attention ; 4 points per block
// ---------------------------------------------------------------------------
template<int ACT, bool INPLACE> // ACT 0: linear, 1: elu, 2: linear*dis*F_nn
__device__ __forceinline__ void layerW(
    const u16* inB, u16* outB, const char* __restrict__ Wt,
    const float* __restrict__ bias, const float* __restrict__ F,
    const int* sidx, const float* sdis)
{
    const int t = threadIdx.x, l = t & 63;
    const int m0 = ((t >> 7) & 1) * 64;
    const int n0 = ((t >> 6) & 1) * 64;
    const int hi = l >> 4;
    f32x4 acc[4][4];
    #pragma unroll
    for (int i = 0; i < 4; i++)
        #pragma unroll
        for (int j = 0; j < 4; j++) acc[i][j] = 0.f;
    gemm_WA(Wt, 256, 0, inB, acc);
    if (INPLACE) __syncthreads();
    #pragma unroll
    for (int mt = 0; mt < 4; mt++){
        int ch0 = m0 + mt * 16 + (hi << 2);
        float4 bq = *(const float4*)&bias[ch0];
        #pragma unroll
        for (int nt = 0; nt < 4; nt++){
            int xrow = n0 + nt * 16 + (l & 15);
            float v[4];
            #pragma unroll
            for (int j = 0; j < 4; j++) v[j] = acc[mt][nt][j] + ((const float*)&bq)[j];
            if (ACT == 1){
                #pragma unroll
                for (int j = 0; j < 4; j++) v[j] = elu_f(v[j]);
            }
            if (ACT == 2){
                float dsc = sdis[xrow];
                float4 fq = *(const float4*)&F[(size_t)sidx[xrow] * ND + ch0];
                #pragma unroll
                for (int j = 0; j < 4; j++) v[j] *= dsc * ((const float*)&fq)[j];
            }
            *(u64*)((char*)outB + (xrow << 8) + (((ch0 << 1)) ^ ((xrow & 7) << 4))) =
                pack4(v[0], v[1], v[2], v[3]);
        }
    }
    __syncthreads();
}

__global__ __launch_bounds__(256, 2) void attn_kernel(
    const float* __restrict__ F, const float* __restrict__ X,
    const float* __restrict__ NUV, const int* __restrict__ TOPK,
    const float* __restrict__ gb1, const float* __restrict__ gb2,
    const float* __restrict__ kb1, const float* __restrict__ kb2,
    const float* __restrict__ vb1, const float* __restrict__ vb2,
    const char* __restrict__ ws, const u16* __restrict__ Qg, u16* __restrict__ ATT)
{
    __shared__ __align__(16) u16 bufA[16384];
    __shared__ __align__(16) u16 bufB[16384];
    __shared__ __align__(16) u16 sP16[2048];   // 4 pts x [16 h][32 k] (64B rows)
    __shared__ float sdis[128];
    __shared__ int   sidx[128];

    const int t = threadIdx.x;
    const int pid0 = blockIdx.x * 4;
    const int l = t & 63;
    const int hi = l >> 4;

    // geometry: RL -> bufB as [128][32] bf16 (swizzled (r&3)<<4, k 12..31 zero)
    if (t < 128){
        int p = t >> 5, k = t & 31;
        int pid = pid0 + p;
        int idx = TOPK[(size_t)pid * NNB + k];
        sidx[t] = idx;
        float x0 = X[(size_t)pid * 3 + 0], x1 = X[(size_t)pid * 3 + 1], x2 = X[(size_t)pid * 3 + 2];
        float ox = X[(size_t)idx * 3 + 0] - x0;
        float oy = X[(size_t)idx * 3 + 1] - x1;
        float oz = X[(size_t)idx * 3 + 2] - x2;
        sdis[t] = __expf(-0.5f * (ox * ox + oy * oy + oz * oz));
        float nv[9];
        #pragma unroll
        for (int i = 0; i < 9; i++) nv[i] = NUV[(size_t)pid * 9 + i];
        float f[12];
        #pragma unroll
        for (int i = 0; i < 3; i++)
            f[i] = nv[i * 3 + 0] * ox + nv[i * 3 + 1] * oy + nv[i * 3 + 2] * oz;
        #pragma unroll
        for (int r = 0; r < 3; r++){
            float a0 = NUV[(size_t)idx * 9 + r * 3 + 0];
            float a1 = NUV[(size_t)idx * 9 + r * 3 + 1];
            float a2 = NUV[(size_t)idx * 9 + r * 3 + 2];
            #pragma unroll
            for (int i = 0; i < 3; i++)
                f[3 + r * 3 + i] = nv[i * 3 + 0] * a0 + nv[i * 3 + 1] * a1 + nv[i * 3 + 2] * a2;
        }
        char* rb = (char*)bufB + (t << 6);
        u32 key = (u32)(t & 3) << 4;
        *(u64*)(rb + (0u ^ key))  = pack4(f[0], f[1], f[2], f[3]);
        *(u64*)(rb + (8u ^ key))  = pack4(f[4], f[5], f[6], f[7]);
        *(u64*)(rb + (16u ^ key)) = pack4(f[8], f[9], f[10], f[11]);
        *(u64*)(rb + (24u ^ key)) = 0ULL;
        *(u64*)(rb + (32u ^ key)) = 0ULL;
        *(u64*)(rb + (40u ^ key)) = 0ULL;
        *(u64*)(rb + (48u ^ key)) = 0ULL;
        *(u64*)(rb + (56u ^ key)) = 0ULL;
    }
    __syncthreads();

    // geo L1 (K=32): A=gW1t, B=RL(bufB) -> bufA, elu (packed stores)
    {
        const int m0 = ((t >> 7) & 1) * 64;
        const int n0 = ((t >> 6) & 1) * 64;
        bf16x8 ag[4], bg[4];
        #pragma unroll
        for (int i = 0; i < 4; i++) ag[i] = ldfragG(ws + OFF_GW1T, m0 + i * 16, 64, 0, l);
        #pragma unroll
        for (int i = 0; i < 4; i++) bg[i] = ldfragRL(bufB, n0 + i * 16, l);
        f32x4 acc[4][4];
        #pragma unroll
        for (int i = 0; i < 4; i++)
            #pragma unroll
            for (int j = 0; j < 4; j++) acc[i][j] = 0.f;
        __builtin_amdgcn_s_setprio(1);
        #pragma unroll
        for (int mt = 0; mt < 4; mt++)
            #pragma unroll
            for (int nt = 0; nt < 4; nt++)
                acc[mt][nt] = __builtin_amdgcn_mfma_f32_16x16x32_bf16(ag[mt], bg[nt], acc[mt][nt], 0, 0, 0);
        __builtin_amdgcn_s_setprio(0);
        #pragma unroll
        for (int mt = 0; mt < 4; mt++){
            int ch0 = m0 + mt * 16 + (hi << 2);
            float4 bq = *(const float4*)&gb1[ch0];
            #pragma unroll
            for (int nt = 0; nt < 4; nt++){
                int xrow = n0 + nt * 16 + (l & 15);
                u64 pk = pack4(elu_f(acc[mt][nt][0] + bq.x), elu_f(acc[mt][nt][1] + bq.y),
                               elu_f(acc[mt][nt][2] + bq.z), elu_f(acc[mt][nt][3] + bq.w));
                *(u64*)((char*)bufA + (xrow << 8) + (((ch0 << 1)) ^ ((xrow & 7) << 4))) = pk;
            }
        }
    }
    __syncthreads();

    // ping-pong MFMA layers
    layerW<2, false>(bufA, bufB, ws + OFF_GW2T, gb2, F, sidx, sdis); // geo L2 *dis*F -> G in bufB
    layerW<1, false>(bufB, bufA, ws + OFF_KW1T, kb1, F, sidx, sdis); // K1 -> Hk in bufA
    layerW<0, true >(bufA, bufA, ws + OFF_KW2T, kb2, F, sidx, sdis); // K2 -> K in bufA (in-place)

    // S^T = K @ Q^T per wave (= per point); softmax over k; P -> sP16 [h][k]
    {
        const int w = t >> 6;
        f32x4 s0, s1;
        s0 = 0.f; s1 = 0.f;
        const char* qb = (const char*)Qg + (size_t)(pid0 + w) * 2048
                       + (size_t)(l & 7) * 256 + (size_t)(hi << 4);
        #pragma unroll
        for (int kk = 0; kk < 4; kk++){
            bf16x8 bq = *(const bf16x8*)(qb + kk * 64);
            bf16x8 a0 = ldfrag(bufA, w * 32,      kk * 32, l);
            bf16x8 a1 = ldfrag(bufA, w * 32 + 16, kk * 32, l);
            s0 = __builtin_amdgcn_mfma_f32_16x16x32_bf16(a0, bq, s0, 0, 0, 0);
            s1 = __builtin_amdgcn_mfma_f32_16x16x32_bf16(a1, bq, s1, 0, 0, 0);
        }
        const float RS = 0.08838834764831845f;
        float sv[8];
        #pragma unroll
        for (int mt = 0; mt < 2; mt++)
            #pragma unroll
            for (int j = 0; j < 4; j++){
                int kidx = mt * 16 + (hi << 2) + j;
                float x = (mt ? s1[j] : s0[j]) * RS;
                if (sidx[w * 32 + kidx] == 0) x = -INFINITY;
                sv[mt * 4 + j] = x;
            }
        float mx = sv[0];
        #pragma unroll
        for (int i = 1; i < 8; i++) mx = fmaxf(mx, sv[i]);
        mx = fmaxf(mx, __shfl_xor(mx, 16));
        mx = fmaxf(mx, __shfl_xor(mx, 32));
        float e[8], sum = 0.f;
        #pragma unroll
        for (int i = 0; i < 8; i++){ e[i] = __expf(sv[i] - mx); sum += e[i]; }
        sum += __shfl_xor(sum, 16);
        sum += __shfl_xor(sum, 32);
        float inv = 1.f / sum;
        char* pb = (char*)sP16 + w * 1024 + (l & 15) * 64 + hi * 8;
        *(u64*)(pb)      = pack4(e[0] * inv, e[1] * inv, e[2] * inv, e[3] * inv);
        *(u64*)(pb + 32) = pack4(e[4] * inv, e[5] * inv, e[6] * inv, e[7] * inv);
    }
    __syncthreads();

    layerW<1, false>(bufB, bufA, ws + OFF_VW1T, vb1, F, sidx, sdis); // V1 -> Hv in bufA (K dead)

    // V2 (old orientation): A=Hv rows, B=vW2t -> V^T in bufB (G dead)
    {
        const int m0 = ((t >> 7) & 1) * 64;
        const int n0 = ((t >> 6) & 1) * 64;
        f32x4 a2[4][4];
        #pragma unroll
        for (int i = 0; i < 4; i++)
            #pragma unroll
            for (int j = 0; j < 4; j++) a2[i][j] = 0.f;
        gemm_AW(bufA, ws + OFF_VW2T, a2);
        #pragma unroll
        for (int mt = 0; mt < 4; mt++)
            #pragma unroll
            for (int nt = 0; nt < 4; nt++){
                int ch = n0 + nt * 16 + (l & 15);          // out-channel (col of V)
                float bv = vb2[ch];
                int r0 = m0 + mt * 16 + (hi << 2);         // v-row, 4-contig
                *(u64*)((char*)bufB + (ch << 8) + (((r0 << 1)) ^ ((ch & 7) << 4))) =
                    pack4(a2[mt][nt][0] + bv, a2[mt][nt][1] + bv,
                          a2[mt][nt][2] + bv, a2[mt][nt][3] + bv);
            }
    }
    __syncthreads();

    // PV: O^T = V^T(A) @ P^T(B) -> packed u64 global stores
    {
        const int w = t >> 6;
        int pid = pid0 + w;
        u32 key = ((u32)pid & 7) << 4;
        char* dst = (char*)ATT + (size_t)pid * 2048;
        const bf16x8 pb = *(const bf16x8*)((const char*)sP16 + w * 1024 + (l & 15) * 64 + (hi << 4));
        int h = l & 15;
        #pragma unroll
        for (int nt = 0; nt < 8; nt++){
            f32x4 o;
            o = 0.f;
            bf16x8 av = ldfrag(bufB, nt * 16, w * 32, l);
            o = __builtin_amdgcn_mfma_f32_16x16x32_bf16(av, pb, o, 0, 0, 0);
            if (h < 8){
                u32 dbyte = (u32)(nt * 32 + hi * 8);
                *(u64*)(dst + h * 256 + (dbyte ^ key)) = pack4(o[0], o[1], o[2], o[3]);
            }
        }
    }
}

// ---------------------------------------------------------------------------
// decode: out = LN( elu(ATT@dW1+db1)@dW2+db2 + F ) * g + b
// ---------------------------------------------------------------------------
__global__ __launch_bounds__(256, 2) void decode_kernel(
    const u16* __restrict__ ATT,
    const float* __restrict__ db1, const float* __restrict__ db2,
    const float* __restrict__ F,
    const float* __restrict__ lng, const float* __restrict__ lnb,
    const char* __restrict__ ws, float* __restrict__ OUT, int n)
{
    __shared__ __align__(16) char SM[67584];
    u16* sA = (u16*)SM;              // [128][128] bf16 (staged from ATT, pre-swizzled)
    u16* sH = (u16*)(SM + 32768);    // hidden, swizzled
    float* sO = (float*)SM;          // [128][132] f32 (aliases sA/sH after L2)

    const int t = threadIdx.x;
    const int row0 = blockIdx.x * 128;
    const int l = t & 63;
    const int m0 = ((t >> 7) & 1) * 64;
    const int n0 = ((t >> 6) & 1) * 64;
    const int hi = l >> 4;

    // L1: 1024 -> 128 over 8 K-chunks (A = dW1t from global, B = ATT rows)
    f32x4 acc[4][4];
    #pragma unroll
    for (int i = 0; i < 4; i++)
        #pragma unroll
        for (int j = 0; j < 4; j++) acc[i][j] = 0.f;
    for (int kc = 0; kc < 8; kc++){
        stage_rows((char*)sA, (const char*)ATT + (size_t)row0 * 2048 + kc * 256, 2048);
        __syncthreads();
        gemm_WA(ws + OFF_DW1T, 2048, kc * 128, sA, acc);
        __syncthreads();
    }
    #pragma unroll
    for (int mt = 0; mt < 4; mt++){
        int ch0 = m0 + mt * 16 + (hi << 2);
        float4 bq = *(const float4*)&db1[ch0];
        #pragma unroll
        for (int nt = 0; nt < 4; nt++){
            int xrow = n0 + nt * 16 + (l & 15);
            u64 pk = pack4(elu_f(acc[mt][nt][0] + bq.x), elu_f(acc[mt][nt][1] + bq.y),
                           elu_f(acc[mt][nt][2] + bq.z), elu_f(acc[mt][nt][3] + bq.w));
            *(u64*)((char*)sH + (xrow << 8) + (((ch0 << 1)) ^ ((xrow & 7) << 4))) = pk;
        }
    }
    __syncthreads();

    // L2
    f32x4 a2[4][4];
    #pragma unroll
    for (int i = 0; i < 4; i++)
        #pragma unroll
        for (int j = 0; j < 4; j++) a2[i][j] = 0.f;
    gemm_WA(ws + OFF_DW2T, 256, 0, sH, a2);
    __syncthreads();   // sA/sH dead; sO may alias

    #pragma unroll
    for (int mt = 0; mt < 4; mt++){
        int ch0 = m0 + mt * 16 + (hi << 2);
        float4 bq = *(const float4*)&db2[ch0];
        #pragma unroll
        for (int nt = 0; nt < 4; nt++){
            int xrow = n0 + nt * 16 + (l & 15);
            int gr = row0 + xrow;
            float4 fres = make_float4(0.f, 0.f, 0.f, 0.f);
            if (gr < n) fres = *(const float4*)&F[(size_t)gr * ND + ch0];
            float4 ov = make_float4(a2[mt][nt][0] + bq.x + fres.x,
                                    a2[mt][nt][1] + bq.y + fres.y,
                                    a2[mt][nt][2] + bq.z + fres.z,
                                    a2[mt][nt][3] + bq.w + fres.w);
            *(float4*)&sO[xrow * 132 + ch0] = ov;
        }
    }
    __syncthreads();

    // LayerNorm: 2 threads per row
    {
        int r = t >> 1, half = t & 1;
        const float* rowp = sO + r * 132 + half * 64;
        float s = 0.f;
        #pragma unroll
        for (int i = 0; i < 16; i++){
            float4 v = ((const float4*)rowp)[i];
            s += v.x + v.y + v.z + v.w;
        }
        s += __shfl_xor(s, 1);
        float mu = s * (1.0f / 128.0f);
        float q = 0.f;
        #pragma unroll
        for (int i = 0; i < 16; i++){
            float4 v = ((const float4*)rowp)[i];
            q += (v.x - mu) * (v.x - mu) + (v.y - mu) * (v.y - mu)
               + (v.z - mu) * (v.z - mu) + (v.w - mu) * (v.w - mu);
        }
        q += __shfl_xor(q, 1);
        float rstd = rsqrtf(q * (1.0f / 128.0f) + 1e-5f);
        int gr = row0 + r;
        if (gr < n){
            #pragma unroll
            for (int i = 0; i < 16; i++){
                float4 v = ((const float4*)rowp)[i];
                int c = half * 64 + i * 4;
                float4 g4 = *(const float4*)&lng[c];
                float4 b4 = *(const float4*)&lnb[c];
                float4 ov = make_float4((v.x - mu) * rstd * g4.x + b4.x,
                                        (v.y - mu) * rstd * g4.y + b4.y,
                                        (v.z - mu) * rstd * g4.z + b4.z,
                                        (v.w - mu) * rstd * g4.w + b4.w);
                *(float4*)&OUT[(size_t)gr * ND + c] = ov;
            }
        }
    }
}

// ---------------------------------------------------------------------------
extern "C" void kernel_launch(void* const* d_in, const int* in_sizes, int n_in,
                              void* d_out, int out_size, void* d_ws, size_t ws_size,
                              hipStream_t stream)
{
    const float* F    = (const float*)d_in[0];
    const float* X    = (const float*)d_in[1];
    const float* NUV  = (const float*)d_in[2];
    const int*   TOPK = (const int*)d_in[3];
    const float* qW1  = (const float*)d_in[4];
    const float* qb1  = (const float*)d_in[5];
    const float* qW2  = (const float*)d_in[6];
    const float* qb2  = (const float*)d_in[7];
    const float* gW1  = (const float*)d_in[8];
    const float* gb1  = (const float*)d_in[9];
    const float* gW2  = (const float*)d_in[10];
    const float* gb2  = (const float*)d_in[11];
    const float* kW1  = (const float*)d_in[12];
    const float* kb1  = (const float*)d_in[13];
    const float* kW2  = (const float*)d_in[14];
    const float* kb2  = (const float*)d_in[15];
    const float* vW1  = (const float*)d_in[16];
    const float* vb1  = (const float*)d_in[17];
    const float* vW2  = (const float*)d_in[18];
    const float* vb2  = (const float*)d_in[19];
    const float* dW1  = (const float*)d_in[20];
    const float* db1  = (const float*)d_in[21];
    const float* dW2  = (const float*)d_in[22];
    const float* db2  = (const float*)d_in[23];
    const float* lng  = (const float*)d_in[24];
    const float* lnb  = (const float*)d_in[25];

    const int n = in_sizes[0] / ND;
    char* wsb = (char*)d_ws;

    PrepDesc pd;
    const float* srcs[10] = {qW1, qW2, gW1, gW2, kW1, kW2, vW1, vW2, dW1, dW2};
    u64 offs[10] = {OFF_QW1T, OFF_QW2T, OFF_GW1T, OFF_GW2T, OFF_KW1T,
                    OFF_KW2T, OFF_VW1T, OFF_VW2T, OFF_DW1T, OFF_DW2T};
    int Ns[10]   = {128, 1024, 128, 128, 128, 128, 128, 128, 128, 128};
    int Ksrc[10] = {128, 128, 12, 128, 128, 128, 128, 128, 1024, 128};
    int Kdst[10] = {128, 128, 32, 128, 128, 128, 128, 128, 1024, 128};
    for (int i = 0; i < 10; i++){
        pd.src[i] = srcs[i]; pd.dstoff[i] = offs[i];
        pd.N[i] = Ns[i]; pd.Ksrc[i] = Ksrc[i]; pd.Kdst[i] = Kdst[i];
    }
    prep_weights<<<186, 256, 0, stream>>>(pd, wsb);

    u16* Qg  = (u16*)(wsb + OFF_Q);
    u16* ATT = (u16*)(wsb + OFF_ATT);
    const int nb = (n + 127) / 128;

    qmlp_kernel<<<nb, 256, 0, stream>>>(F, qb1, qb2, wsb, Qg, n);
    attn_kernel<<<n / 4, 256, 0, stream>>>(F, X, NUV, TOPK, gb1, gb2,
                                           kb1, kb2, vb1, vb2, wsb, Qg, ATT);
    decode_kernel<<<nb, 256, 0, stream>>>(ATT, db1, db2, F, lng, lnb, wsb, (float*)d_out, n);
}